// Round 6
// baseline (179.691 us; speedup 1.0000x reference)
//
#include <hip/hip_runtime.h>

#define N_NODES 50000
#define N_EDGES 800000
#define N_GRAPHS 64
#define SCAN_BLOCKS 196              // 196*256 = 50176 >= N_NODES

// CSR build partitioning: zero device atomics
#define NCHUNK 32
#define CHUNK_E (N_EDGES / NCHUNK)   // 25000
#define NRANGE 4
#define RSZ (N_NODES / NRANGE)       // 12500 counters = 50KB LDS

// fat k1 partition
#define K1_HIST (NCHUNK * NRANGE)    // 128 blocks
#define K1_EMBED (N_NODES * 16 / 256) // 3125 blocks
#define K1_PREP 32                   // 8192 threads: weight prep + gsum zero

// quarter-major feature layout: [4][N_NODES][32 feats] bf16
#define QDW (N_NODES * 16)           // dwords per quarter
#define QUS (N_NODES * 32)           // ushorts per quarter

typedef __bf16 bf16x8 __attribute__((ext_vector_type(8)));
typedef float f32x4 __attribute__((ext_vector_type(4)));

// ---- bf16 helpers (RN-even pack, exact unpack) ----
static __device__ __forceinline__ unsigned short f2bf(float f) {
    union { float f; unsigned u; } v; v.f = f;
    unsigned u = v.u;
    u += 0x7fffu + ((u >> 16) & 1u);          // round-to-nearest-even
    return (unsigned short)(u >> 16);
}
static __device__ __forceinline__ float bf2f(unsigned short h) {
    union { unsigned u; float f; } v; v.u = ((unsigned)h) << 16; return v.f;
}
static __device__ __forceinline__ float bflo(unsigned w) {
    union { unsigned u; float f; } v; v.u = w << 16; return v.f;
}
static __device__ __forceinline__ float bfhi(unsigned w) {
    union { unsigned u; float f; } v; v.u = w & 0xffff0000u; return v.f;
}

// ---------------- k1: histpart | embed | weight-prep + gsum zero ----------------
__global__ __launch_bounds__(256) void k1_kernel(const int* __restrict__ dst,
                                                 int* __restrict__ part,
                                                 const int* __restrict__ x_idx,
                                                 const float* __restrict__ table,
                                                 unsigned short* __restrict__ X,
                                                 const float* __restrict__ Wl1,
                                                 const float* __restrict__ Wr1,
                                                 const float* __restrict__ Wl2,
                                                 const float* __restrict__ Wr2,
                                                 unsigned short* __restrict__ blob,
                                                 float* __restrict__ gsum) {
    const int b = blockIdx.x;
    if (b < K1_HIST) {
        // ---- per-(chunk,range) LDS histogram of dst ----
        __shared__ int h[RSZ];
        const int c = b >> 2;            // chunk
        const int r = b & 3;             // node range
        const int rbase = r * RSZ;
        for (int i = threadIdx.x; i < RSZ; i += 256) h[i] = 0;
        __syncthreads();
        const int4* d4 = (const int4*)(dst + c * CHUNK_E);
        for (int i = threadIdx.x; i < CHUNK_E / 4; i += 256) {
            int4 d = d4[i];
            unsigned a;
            a = (unsigned)(d.x - rbase); if (a < RSZ) atomicAdd(&h[a], 1);
            a = (unsigned)(d.y - rbase); if (a < RSZ) atomicAdd(&h[a], 1);
            a = (unsigned)(d.z - rbase); if (a < RSZ) atomicAdd(&h[a], 1);
            a = (unsigned)(d.w - rbase); if (a < RSZ) atomicAdd(&h[a], 1);
        }
        __syncthreads();
        int* p = part + (size_t)c * N_NODES + rbase;
        for (int i = threadIdx.x; i < RSZ; i += 256) p[i] = h[i];
    } else if (b < K1_HIST + K1_EMBED) {
        // ---- embedding gather -> bf16, quarter-major store ----
        int i = (b - K1_HIST) * 256 + threadIdx.x;   // node*16 + 8-feat chunk
        int n = i >> 4, cq = i & 15;
        const float4* src = (const float4*)(table + (size_t)x_idx[n] * 128 + cq * 8);
        float4 a = src[0], bb = src[1];
        uint4 o;
        o.x = (unsigned)f2bf(a.x)  | ((unsigned)f2bf(a.y)  << 16);
        o.y = (unsigned)f2bf(a.z)  | ((unsigned)f2bf(a.w)  << 16);
        o.z = (unsigned)f2bf(bb.x) | ((unsigned)f2bf(bb.y) << 16);
        o.w = (unsigned)f2bf(bb.z) | ((unsigned)f2bf(bb.w) << 16);
        int qq = cq >> 2;                            // quarter
        ((uint4*)X)[(size_t)qq * (N_NODES * 4) + n * 4 + (cq & 3)] = o;
    } else {
        // ---- weight prep (frag-ordered bf16 blob) + gsum zero ----
        int s = (b - K1_HIST - K1_EMBED) * 256 + threadIdx.x;   // [0, 8192)
        gsum[s] = 0.f;
        int g = s >> 12;
        int sl = s & 4095;
        int fidx = sl >> 6, lane = sl & 63;
        int m = fidx >> 5, kk = (fidx >> 3) & 3, tile = fidx & 7;
        const float* W = g ? (m ? Wr2 : Wl2) : (m ? Wr1 : Wl1);
        int n  = tile * 16 + (lane & 15);
        int k0 = kk * 32 + (lane >> 4) * 8;
        const float4* src = (const float4*)(W + n * 128 + k0);
        float4 a = src[0], bb = src[1];
        uint4 o;
        o.x = (unsigned)f2bf(a.x)  | ((unsigned)f2bf(a.y)  << 16);
        o.y = (unsigned)f2bf(a.z)  | ((unsigned)f2bf(a.w)  << 16);
        o.z = (unsigned)f2bf(bb.x) | ((unsigned)f2bf(bb.y) << 16);
        o.w = (unsigned)f2bf(bb.z) | ((unsigned)f2bf(bb.w) << 16);
        ((uint4*)blob)[s] = o;
    }
}

// ---------------- cnt + per-block sum (fused) ----------------
__global__ __launch_bounds__(256) void cntsum_kernel(const int* __restrict__ part,
                                                     int* __restrict__ cnt,
                                                     int* __restrict__ bsum) {
    int t = threadIdx.x;
    int n = blockIdx.x * 256 + t;
    int s = 0;
    if (n < N_NODES) {
#pragma unroll
        for (int c = 0; c < NCHUNK; ++c) s += part[(size_t)c * N_NODES + n];
        cnt[n] = s;
    }
#pragma unroll
    for (int off = 32; off > 0; off >>= 1) s += __shfl_down(s, off, 64);
    __shared__ int ws[4];
    if ((t & 63) == 0) ws[t >> 6] = s;
    __syncthreads();
    if (t == 0) bsum[blockIdx.x] = ws[0] + ws[1] + ws[2] + ws[3];
}

// ---------------- rowptr + per-chunk offsets (with inline block-offset scan) ----------------
__global__ __launch_bounds__(256) void rowptroff_kernel(const int* __restrict__ cnt,
                                                        const int* __restrict__ bsum,
                                                        const int* __restrict__ part,
                                                        int* __restrict__ rowptr,
                                                        int* __restrict__ off) {
    __shared__ int sb[256];
    __shared__ int sd[256];
    int t = threadIdx.x;
    // inline scan of the 196 block sums (redundant per block, ~free)
    sb[t] = (t < SCAN_BLOCKS) ? bsum[t] : 0;
    __syncthreads();
    for (int o = 1; o < 256; o <<= 1) {
        int add = (t >= o) ? sb[t - o] : 0;
        __syncthreads();
        sb[t] += add;
        __syncthreads();
    }
    int boff = (blockIdx.x > 0) ? sb[blockIdx.x - 1] : 0;

    int i = blockIdx.x * 256 + t;
    int v = (i < N_NODES) ? cnt[i] : 0;
    sd[t] = v;
    __syncthreads();
    for (int o = 1; o < 256; o <<= 1) {
        int add = (t >= o) ? sd[t - o] : 0;
        __syncthreads();
        sd[t] += add;
        __syncthreads();
    }
    int excl = sd[t] - v + boff;
    if (i < N_NODES) {
        rowptr[i] = excl;
        if (i == N_NODES - 1) rowptr[N_NODES] = excl + v;
        int run = excl;
#pragma unroll
        for (int c = 0; c < NCHUNK; ++c) {
            off[(size_t)c * N_NODES + i] = run;
            run += part[(size_t)c * N_NODES + i];
        }
    }
}

// ---------------- scatter, LDS position counters, no device atomics ----------------
__global__ __launch_bounds__(256) void scatter_kernel(const int* __restrict__ src,
                                                      const int* __restrict__ dst,
                                                      const int* __restrict__ off,
                                                      int* __restrict__ csr) {
    __shared__ int h[RSZ];
    const int c = blockIdx.x >> 2;
    const int r = blockIdx.x & 3;
    const int rbase = r * RSZ;
    const int* o = off + (size_t)c * N_NODES + rbase;
    for (int i = threadIdx.x; i < RSZ; i += 256) h[i] = o[i];
    __syncthreads();
    const int4* d4 = (const int4*)(dst + c * CHUNK_E);
    const int4* s4 = (const int4*)(src + c * CHUNK_E);
    for (int i = threadIdx.x; i < CHUNK_E / 4; i += 256) {
        int4 d = d4[i];
        int4 s = s4[i];
        unsigned a;
        a = (unsigned)(d.x - rbase); if (a < RSZ) csr[atomicAdd(&h[a], 1)] = s.x;
        a = (unsigned)(d.y - rbase); if (a < RSZ) csr[atomicAdd(&h[a], 1)] = s.y;
        a = (unsigned)(d.z - rbase); if (a < RSZ) csr[atomicAdd(&h[a], 1)] = s.z;
        a = (unsigned)(d.w - rbase); if (a < RSZ) csr[atomicAdd(&h[a], 1)] = s.w;
    }
}

// ---------------- mean aggregation, quarter-blocked for L2 residency ----------------
// grid (3125, 4): blockIdx.y = feature quarter (slow-varying -> all quarter-0
// blocks dispatch first; 3.2MB quarter fits every XCD's 4MiB L2).
// wave = 4 nodes x 16 lanes; lane f = 1 dword = 2 feats of the quarter.
__global__ __launch_bounds__(256) void agg_kernel(const unsigned* __restrict__ Xq,
                                                  const int* __restrict__ rowptr,
                                                  const int* __restrict__ csr,
                                                  unsigned* __restrict__ AGGq) {
    const int t = threadIdx.x;
    const int lane = t & 63;
    const int g = lane >> 4;                 // node group within wave
    const int f = lane & 15;                 // dword within quarter
    const int n = blockIdx.x * 16 + (t >> 6) * 4 + g;
    const unsigned* Xb = Xq + (size_t)blockIdx.y * QDW;
    int beg = rowptr[n], end = rowptr[n + 1];
    float sx = 0.f, sy = 0.f;
    int i = beg;
    for (; i + 4 <= end; i += 4) {           // 4-deep to overlap gather latency
        int s0 = csr[i], s1 = csr[i + 1], s2 = csr[i + 2], s3 = csr[i + 3];
        unsigned v0 = Xb[(size_t)s0 * 16 + f];
        unsigned v1 = Xb[(size_t)s1 * 16 + f];
        unsigned v2 = Xb[(size_t)s2 * 16 + f];
        unsigned v3 = Xb[(size_t)s3 * 16 + f];
        sx += (bflo(v0) + bflo(v1)) + (bflo(v2) + bflo(v3));
        sy += (bfhi(v0) + bfhi(v1)) + (bfhi(v2) + bfhi(v3));
    }
    for (; i < end; ++i) {
        unsigned v = Xb[(size_t)csr[i] * 16 + f];
        sx += bflo(v); sy += bfhi(v);
    }
    float inv = 1.f / (float)max(end - beg, 1);
    AGGq[(size_t)blockIdx.y * QDW + (size_t)n * 16 + f] =
        (unsigned)f2bf(sx * inv) | ((unsigned)f2bf(sy * inv) << 16);
}

// ---------------- fused SAGE linear via MFMA (layer 1: writes quartered Y) ----------------
// A0/A1/Y quarter-major [4][N][32]. k-fragment quarter = km&3 (aligned by design).
__global__ __launch_bounds__(256) void gemm_kernel(const unsigned short* __restrict__ A0,
                                                   const unsigned short* __restrict__ A1,
                                                   const unsigned short* __restrict__ wblob,
                                                   const float* __restrict__ bias,
                                                   unsigned short* __restrict__ Y) {
    __shared__ char lds[65536];
    const int t = threadIdx.x, lane = t & 63, w = t >> 6;
    const int row0 = blockIdx.x * 128 + w * 32;

    {
        const char* src = (const char*)wblob + w * 16384 + lane * 16;
        char* dst = lds + w * 16384;
#pragma unroll
        for (int i = 0; i < 16; ++i) {
            __builtin_amdgcn_global_load_lds(
                (const __attribute__((address_space(1))) unsigned*)(src + i * 1024),
                (__attribute__((address_space(3))) unsigned*)(dst + i * 1024), 16, 0, 0);
        }
    }
    __syncthreads();

    f32x4 acc[2][8];
#pragma unroll
    for (int rt = 0; rt < 2; ++rt)
#pragma unroll
        for (int tl = 0; tl < 8; ++tl) acc[rt][tl] = (f32x4){0.f, 0.f, 0.f, 0.f};

    int rA = min(row0 + (lane & 15),      N_NODES - 1);
    int rB = min(row0 + 16 + (lane & 15), N_NODES - 1);
    const int kl = (lane >> 4) * 8;          // ushort offset within quarter row

#pragma unroll
    for (int km = 0; km < 8; ++km) {
        const unsigned short* Aq = ((km < 4) ? A0 : A1) + (size_t)(km & 3) * QUS;
        bf16x8 a0 = *(const bf16x8*)(Aq + (size_t)rA * 32 + kl);
        bf16x8 a1 = *(const bf16x8*)(Aq + (size_t)rB * 32 + kl);
        const char* bbase = lds + km * 8192 + lane * 16;
#pragma unroll
        for (int tile = 0; tile < 8; ++tile) {
            bf16x8 b = *(const bf16x8*)(bbase + tile * 1024);
            acc[0][tile] = __builtin_amdgcn_mfma_f32_16x16x32_bf16(a0, b, acc[0][tile], 0, 0, 0);
            acc[1][tile] = __builtin_amdgcn_mfma_f32_16x16x32_bf16(a1, b, acc[1][tile], 0, 0, 0);
        }
    }

    const int c     = lane & 15;
    const int rbase = (lane >> 4) * 4;
#pragma unroll
    for (int rt = 0; rt < 2; ++rt) {
#pragma unroll
        for (int tile = 0; tile < 8; ++tile) {
            int col = tile * 16 + c;
            float bv = bias[col];
            int q = col >> 5, wc = col & 31;
#pragma unroll
            for (int j = 0; j < 4; ++j) {
                int r = row0 + rt * 16 + rbase + j;
                if (r < N_NODES)
                    Y[(size_t)q * QUS + (size_t)r * 32 + wc] =
                        f2bf(fmaxf(acc[rt][tile][j] + bv, 0.f));
            }
        }
    }
}

// ---------------- layer-2 GEMM with fused mean-pool (no y2 write) ----------------
__global__ __launch_bounds__(256) void gemm_pool_kernel(const unsigned short* __restrict__ A0,
                                                        const unsigned short* __restrict__ A1,
                                                        const unsigned short* __restrict__ wblob,
                                                        const float* __restrict__ bias,
                                                        const int* __restrict__ batch,
                                                        float* __restrict__ gsum) {
    __shared__ char lds[65536];
    const int t = threadIdx.x, lane = t & 63, w = t >> 6;
    const int brow0 = blockIdx.x * 128;
    const int row0  = brow0 + w * 32;

    {
        const char* src = (const char*)wblob + w * 16384 + lane * 16;
        char* dst = lds + w * 16384;
#pragma unroll
        for (int i = 0; i < 16; ++i) {
            __builtin_amdgcn_global_load_lds(
                (const __attribute__((address_space(1))) unsigned*)(src + i * 1024),
                (__attribute__((address_space(3))) unsigned*)(dst + i * 1024), 16, 0, 0);
        }
    }
    __syncthreads();

    f32x4 acc[2][8];
#pragma unroll
    for (int rt = 0; rt < 2; ++rt)
#pragma unroll
        for (int tl = 0; tl < 8; ++tl) acc[rt][tl] = (f32x4){0.f, 0.f, 0.f, 0.f};

    int rA = min(row0 + (lane & 15),      N_NODES - 1);
    int rB = min(row0 + 16 + (lane & 15), N_NODES - 1);
    const int kl = (lane >> 4) * 8;

#pragma unroll
    for (int km = 0; km < 8; ++km) {
        const unsigned short* Aq = ((km < 4) ? A0 : A1) + (size_t)(km & 3) * QUS;
        bf16x8 a0 = *(const bf16x8*)(Aq + (size_t)rA * 32 + kl);
        bf16x8 a1 = *(const bf16x8*)(Aq + (size_t)rB * 32 + kl);
        const char* bbase = lds + km * 8192 + lane * 16;
#pragma unroll
        for (int tile = 0; tile < 8; ++tile) {
            bf16x8 b = *(const bf16x8*)(bbase + tile * 1024);
            acc[0][tile] = __builtin_amdgcn_mfma_f32_16x16x32_bf16(a0, b, acc[0][tile], 0, 0, 0);
            acc[1][tile] = __builtin_amdgcn_mfma_f32_16x16x32_bf16(a1, b, acc[1][tile], 0, 0, 0);
        }
    }

    // epilogue: relu(acc+bias) -> reuse weight LDS as 128x128 f32 tile
    __syncthreads();                       // all waves done reading weights
    float* ftile = (float*)lds;
    const int c     = lane & 15;
    const int rbase = (lane >> 4) * 4;
#pragma unroll
    for (int rt = 0; rt < 2; ++rt) {
#pragma unroll
        for (int tile = 0; tile < 8; ++tile) {
            int col = tile * 16 + c;
            float bv = bias[col];
#pragma unroll
            for (int j = 0; j < 4; ++j) {
                int lr = w * 32 + rt * 16 + rbase + j;
                ftile[lr * 128 + col] = fmaxf(acc[rt][tile][j] + bv, 0.f);
            }
        }
    }
    __syncthreads();

    // per-graph column partial sums (batch sorted): thread = (col, row-half)
    const int col  = t & 127;
    const int half = t >> 7;
    float s = 0.f;
    int curg = -1;
    for (int rr = 0; rr < 64; ++rr) {
        int r = brow0 + half * 64 + rr;
        if (r >= N_NODES) break;
        int g = batch[r];
        if (g != curg) {
            if (curg >= 0) atomicAdd(&gsum[curg * 128 + col], s);
            curg = g; s = 0.f;
        }
        s += ftile[(half * 64 + rr) * 128 + col];
    }
    if (curg >= 0) atomicAdd(&gsum[curg * 128 + col], s);
}

// ---------------- classifier ----------------
__global__ void final_kernel(const float* __restrict__ gsum, const int* __restrict__ batch,
                             const float* __restrict__ linW, const float* __restrict__ linb,
                             float* __restrict__ out) {
    int t = blockIdx.x * 256 + threadIdx.x;
    if (t >= N_GRAPHS * 10) return;
    int g = t / 10, j = t % 10;
    int bnd[2];
    for (int c = 0; c < 2; ++c) {
        int target = g + c;
        int lo = 0, hi = N_NODES;
        while (lo < hi) { int mid = (lo + hi) >> 1; if (batch[mid] < target) lo = mid + 1; else hi = mid; }
        bnd[c] = lo;
    }
    float invc = 1.f / (float)max(bnd[1] - bnd[0], 1);
    float s = 0.f;
    for (int k = 0; k < 128; ++k) s += gsum[g * 128 + k] * linW[j * 128 + k];
    out[t] = linb[j] + s * invc;
}

extern "C" void kernel_launch(void* const* d_in, const int* in_sizes, int n_in,
                              void* d_out, int out_size, void* d_ws, size_t ws_size,
                              hipStream_t stream) {
    const int*   x_idx = (const int*)d_in[0];
    const int*   eidx  = (const int*)d_in[1];   // [2][N_EDGES]
    const int*   batch = (const int*)d_in[2];
    const float* table = (const float*)d_in[3];
    const float* Wl1   = (const float*)d_in[4];
    const float* bl1   = (const float*)d_in[5];
    const float* Wr1   = (const float*)d_in[6];
    const float* Wl2   = (const float*)d_in[7];
    const float* bl2   = (const float*)d_in[8];
    const float* Wr2   = (const float*)d_in[9];
    const float* linW  = (const float*)d_in[10];
    const float* linb  = (const float*)d_in[11];
    float*       out   = (float*)d_out;

    const int* src = eidx;
    const int* dst = eidx + N_EDGES;

    // workspace layout (~55 MB); feature buffers quarter-major [4][N][32]
    unsigned short* X    = (unsigned short*)d_ws;                 // x0
    unsigned short* AGG  = X   + (size_t)N_NODES * 128;           // agg
    unsigned short* Y1   = AGG + (size_t)N_NODES * 128;           // y1
    unsigned short* blob = Y1  + (size_t)N_NODES * 128;           // 2 x 64KB frag-ordered
    float* gsum = (float*)(blob + 65536);
    int* cnt    = (int*)(gsum + N_GRAPHS * 128);
    int* rowptr = cnt + N_NODES;                                  // N_NODES+1
    int* csr    = rowptr + (N_NODES + 1);                         // N_EDGES
    int* bsum   = csr + N_EDGES;                                  // SCAN_BLOCKS
    int* part   = bsum + SCAN_BLOCKS;                             // NCHUNK x N_NODES
    int* off    = part + (size_t)NCHUNK * N_NODES;                // NCHUNK x N_NODES

    // k1: histogram | embed | weight prep + gsum zero (one launch)
    k1_kernel<<<K1_HIST + K1_EMBED + K1_PREP, 256, 0, stream>>>(
        dst, part, x_idx, table, X, Wl1, Wr1, Wl2, Wr2, blob, gsum);
    cntsum_kernel   <<<SCAN_BLOCKS, 256, 0, stream>>>(part, cnt, bsum);
    rowptroff_kernel<<<SCAN_BLOCKS, 256, 0, stream>>>(cnt, bsum, part, rowptr, off);
    scatter_kernel  <<<NCHUNK * NRANGE, 256, 0, stream>>>(src, dst, off, csr);

    // layer 1
    agg_kernel <<<dim3(N_NODES / 16, 4), 256, 0, stream>>>((const unsigned*)X, rowptr, csr, (unsigned*)AGG);
    gemm_kernel<<<dim3((N_NODES + 127) / 128), 256, 0, stream>>>(AGG, X, blob, bl1, Y1);
    // layer 2 (+ fused mean pool)
    agg_kernel      <<<dim3(N_NODES / 16, 4), 256, 0, stream>>>((const unsigned*)Y1, rowptr, csr, (unsigned*)AGG);
    gemm_pool_kernel<<<dim3((N_NODES + 127) / 128), 256, 0, stream>>>(AGG, Y1, blob + 32768, bl2, batch, gsum);

    final_kernel<<<3, 256, 0, stream>>>(gsum, batch, linW, linb, out);
}

// Round 7
// 153.491 us; speedup vs baseline: 1.1707x; 1.1707x over previous
//
#include <hip/hip_runtime.h>

#define N_NODES 50000
#define N_EDGES 800000
#define N_GRAPHS 64
#define SCAN_BLOCKS 196              // 196*256 = 50176 >= N_NODES

// CSR build partitioning: zero device atomics
#define NCHUNK 32
#define CHUNK_E (N_EDGES / NCHUNK)   // 25000
#define NRANGE 4
#define RSZ (N_NODES / NRANGE)       // 12500 counters = 50KB LDS

// fat k1 partition
#define K1_HIST (NCHUNK * NRANGE)    // 128 blocks
#define K1_EMBED (N_NODES * 16 / 256) // 3125 blocks
#define K1_PREP 32                   // 8192 threads: weight prep + gsum zero

typedef __bf16 bf16x8 __attribute__((ext_vector_type(8)));
typedef float f32x4 __attribute__((ext_vector_type(4)));

// ---- bf16 helpers (RN-even pack, exact unpack) ----
static __device__ __forceinline__ unsigned short f2bf(float f) {
    union { float f; unsigned u; } v; v.f = f;
    unsigned u = v.u;
    u += 0x7fffu + ((u >> 16) & 1u);          // round-to-nearest-even
    return (unsigned short)(u >> 16);
}
static __device__ __forceinline__ float bflo(unsigned w) {
    union { unsigned u; float f; } v; v.u = w << 16; return v.f;
}
static __device__ __forceinline__ float bfhi(unsigned w) {
    union { unsigned u; float f; } v; v.u = w & 0xffff0000u; return v.f;
}

// ---------------- k1: histpart | embed | weight-prep + gsum zero ----------------
__global__ __launch_bounds__(256) void k1_kernel(const int* __restrict__ dst,
                                                 int* __restrict__ part,
                                                 const int* __restrict__ x_idx,
                                                 const float* __restrict__ table,
                                                 unsigned short* __restrict__ X,
                                                 const float* __restrict__ Wl1,
                                                 const float* __restrict__ Wr1,
                                                 const float* __restrict__ Wl2,
                                                 const float* __restrict__ Wr2,
                                                 unsigned short* __restrict__ blob,
                                                 float* __restrict__ gsum) {
    const int b = blockIdx.x;
    if (b < K1_HIST) {
        // ---- per-(chunk,range) LDS histogram of dst ----
        __shared__ int h[RSZ];
        const int c = b >> 2;            // chunk
        const int r = b & 3;             // node range
        const int rbase = r * RSZ;
        for (int i = threadIdx.x; i < RSZ; i += 256) h[i] = 0;
        __syncthreads();
        const int4* d4 = (const int4*)(dst + c * CHUNK_E);
        for (int i = threadIdx.x; i < CHUNK_E / 4; i += 256) {
            int4 d = d4[i];
            unsigned a;
            a = (unsigned)(d.x - rbase); if (a < RSZ) atomicAdd(&h[a], 1);
            a = (unsigned)(d.y - rbase); if (a < RSZ) atomicAdd(&h[a], 1);
            a = (unsigned)(d.z - rbase); if (a < RSZ) atomicAdd(&h[a], 1);
            a = (unsigned)(d.w - rbase); if (a < RSZ) atomicAdd(&h[a], 1);
        }
        __syncthreads();
        int* p = part + (size_t)c * N_NODES + rbase;
        for (int i = threadIdx.x; i < RSZ; i += 256) p[i] = h[i];
    } else if (b < K1_HIST + K1_EMBED) {
        // ---- embedding gather -> bf16, full-row store ----
        int i = (b - K1_HIST) * 256 + threadIdx.x;   // node*16 + 8-feat chunk
        int n = i >> 4, cq = i & 15;
        const float4* src = (const float4*)(table + (size_t)x_idx[n] * 128 + cq * 8);
        float4 a = src[0], bb = src[1];
        uint4 o;
        o.x = (unsigned)f2bf(a.x)  | ((unsigned)f2bf(a.y)  << 16);
        o.y = (unsigned)f2bf(a.z)  | ((unsigned)f2bf(a.w)  << 16);
        o.z = (unsigned)f2bf(bb.x) | ((unsigned)f2bf(bb.y) << 16);
        o.w = (unsigned)f2bf(bb.z) | ((unsigned)f2bf(bb.w) << 16);
        ((uint4*)X)[i] = o;
    } else {
        // ---- weight prep (frag-ordered bf16 blob) + gsum zero ----
        int s = (b - K1_HIST - K1_EMBED) * 256 + threadIdx.x;   // [0, 8192)
        gsum[s] = 0.f;
        int g = s >> 12;
        int sl = s & 4095;
        int fidx = sl >> 6, lane = sl & 63;
        int m = fidx >> 5, kk = (fidx >> 3) & 3, tile = fidx & 7;
        const float* W = g ? (m ? Wr2 : Wl2) : (m ? Wr1 : Wl1);
        int n  = tile * 16 + (lane & 15);
        int k0 = kk * 32 + (lane >> 4) * 8;
        const float4* src = (const float4*)(W + n * 128 + k0);
        float4 a = src[0], bb = src[1];
        uint4 o;
        o.x = (unsigned)f2bf(a.x)  | ((unsigned)f2bf(a.y)  << 16);
        o.y = (unsigned)f2bf(a.z)  | ((unsigned)f2bf(a.w)  << 16);
        o.z = (unsigned)f2bf(bb.x) | ((unsigned)f2bf(bb.y) << 16);
        o.w = (unsigned)f2bf(bb.z) | ((unsigned)f2bf(bb.w) << 16);
        ((uint4*)blob)[s] = o;
    }
}

// ---------------- cnt + per-block sum (fused) ----------------
__global__ __launch_bounds__(256) void cntsum_kernel(const int* __restrict__ part,
                                                     int* __restrict__ cnt,
                                                     int* __restrict__ bsum) {
    int t = threadIdx.x;
    int n = blockIdx.x * 256 + t;
    int s = 0;
    if (n < N_NODES) {
#pragma unroll
        for (int c = 0; c < NCHUNK; ++c) s += part[(size_t)c * N_NODES + n];
        cnt[n] = s;
    }
#pragma unroll
    for (int off = 32; off > 0; off >>= 1) s += __shfl_down(s, off, 64);
    __shared__ int ws[4];
    if ((t & 63) == 0) ws[t >> 6] = s;
    __syncthreads();
    if (t == 0) bsum[blockIdx.x] = ws[0] + ws[1] + ws[2] + ws[3];
}

// ---------------- rowptr + per-chunk offsets (with inline block-offset scan) ----------------
__global__ __launch_bounds__(256) void rowptroff_kernel(const int* __restrict__ cnt,
                                                        const int* __restrict__ bsum,
                                                        const int* __restrict__ part,
                                                        int* __restrict__ rowptr,
                                                        int* __restrict__ off) {
    __shared__ int sb[256];
    __shared__ int sd[256];
    int t = threadIdx.x;
    sb[t] = (t < SCAN_BLOCKS) ? bsum[t] : 0;
    __syncthreads();
    for (int o = 1; o < 256; o <<= 1) {
        int add = (t >= o) ? sb[t - o] : 0;
        __syncthreads();
        sb[t] += add;
        __syncthreads();
    }
    int boff = (blockIdx.x > 0) ? sb[blockIdx.x - 1] : 0;

    int i = blockIdx.x * 256 + t;
    int v = (i < N_NODES) ? cnt[i] : 0;
    sd[t] = v;
    __syncthreads();
    for (int o = 1; o < 256; o <<= 1) {
        int add = (t >= o) ? sd[t - o] : 0;
        __syncthreads();
        sd[t] += add;
        __syncthreads();
    }
    int excl = sd[t] - v + boff;
    if (i < N_NODES) {
        rowptr[i] = excl;
        if (i == N_NODES - 1) rowptr[N_NODES] = excl + v;
        int run = excl;
#pragma unroll
        for (int c = 0; c < NCHUNK; ++c) {
            off[(size_t)c * N_NODES + i] = run;
            run += part[(size_t)c * N_NODES + i];
        }
    }
}

// ---------------- scatter, LDS position counters, no device atomics ----------------
__global__ __launch_bounds__(256) void scatter_kernel(const int* __restrict__ src,
                                                      const int* __restrict__ dst,
                                                      const int* __restrict__ off,
                                                      int* __restrict__ csr) {
    __shared__ int h[RSZ];
    const int c = blockIdx.x >> 2;
    const int r = blockIdx.x & 3;
    const int rbase = r * RSZ;
    const int* o = off + (size_t)c * N_NODES + rbase;
    for (int i = threadIdx.x; i < RSZ; i += 256) h[i] = o[i];
    __syncthreads();
    const int4* d4 = (const int4*)(dst + c * CHUNK_E);
    const int4* s4 = (const int4*)(src + c * CHUNK_E);
    for (int i = threadIdx.x; i < CHUNK_E / 4; i += 256) {
        int4 d = d4[i];
        int4 s = s4[i];
        unsigned a;
        a = (unsigned)(d.x - rbase); if (a < RSZ) csr[atomicAdd(&h[a], 1)] = s.x;
        a = (unsigned)(d.y - rbase); if (a < RSZ) csr[atomicAdd(&h[a], 1)] = s.y;
        a = (unsigned)(d.z - rbase); if (a < RSZ) csr[atomicAdd(&h[a], 1)] = s.z;
        a = (unsigned)(d.w - rbase); if (a < RSZ) csr[atomicAdd(&h[a], 1)] = s.w;
    }
}

// ---------------- mean aggregation: 4 nodes/wave, 16 lanes x 16B per row ----------------
// lane (g,f): g = node group (lane>>4), f = 16B chunk (lane&15).
// Per 4-edge unrolled step: 4 x dwordx4 row-gathers + 1 x dwordx4 csr load,
// ~4.5 wave-VALU/edge -- minimizes both VMEM instruction count and unpack VALU.
__global__ __launch_bounds__(256) void agg_kernel(const unsigned short* __restrict__ X,
                                                  const int* __restrict__ rowptr,
                                                  const int* __restrict__ csr,
                                                  unsigned short* __restrict__ AGG) {
    const int t = threadIdx.x;
    const int lane = t & 63;
    const int f = lane & 15;
    const int n = blockIdx.x * 16 + (t >> 6) * 4 + (lane >> 4);
    int beg = rowptr[n], end = rowptr[n + 1];
    const char* Xb = (const char*)X + f * 16;
    float a0 = 0.f, a1 = 0.f, a2 = 0.f, a3 = 0.f,
          a4 = 0.f, a5 = 0.f, a6 = 0.f, a7 = 0.f;
    int i = beg;
    for (; i + 4 <= end; i += 4) {
        int s0 = csr[i], s1 = csr[i + 1], s2 = csr[i + 2], s3 = csr[i + 3];
        uint4 v0 = *(const uint4*)(Xb + (size_t)s0 * 256);
        uint4 v1 = *(const uint4*)(Xb + (size_t)s1 * 256);
        uint4 v2 = *(const uint4*)(Xb + (size_t)s2 * 256);
        uint4 v3 = *(const uint4*)(Xb + (size_t)s3 * 256);
        a0 += (bflo(v0.x) + bflo(v1.x)) + (bflo(v2.x) + bflo(v3.x));
        a1 += (bfhi(v0.x) + bfhi(v1.x)) + (bfhi(v2.x) + bfhi(v3.x));
        a2 += (bflo(v0.y) + bflo(v1.y)) + (bflo(v2.y) + bflo(v3.y));
        a3 += (bfhi(v0.y) + bfhi(v1.y)) + (bfhi(v2.y) + bfhi(v3.y));
        a4 += (bflo(v0.z) + bflo(v1.z)) + (bflo(v2.z) + bflo(v3.z));
        a5 += (bfhi(v0.z) + bfhi(v1.z)) + (bfhi(v2.z) + bfhi(v3.z));
        a6 += (bflo(v0.w) + bflo(v1.w)) + (bflo(v2.w) + bflo(v3.w));
        a7 += (bfhi(v0.w) + bfhi(v1.w)) + (bfhi(v2.w) + bfhi(v3.w));
    }
    for (; i < end; ++i) {
        uint4 v0 = *(const uint4*)(Xb + (size_t)csr[i] * 256);
        a0 += bflo(v0.x); a1 += bfhi(v0.x);
        a2 += bflo(v0.y); a3 += bfhi(v0.y);
        a4 += bflo(v0.z); a5 += bfhi(v0.z);
        a6 += bflo(v0.w); a7 += bfhi(v0.w);
    }
    float inv = 1.f / (float)max(end - beg, 1);
    uint4 o;
    o.x = (unsigned)f2bf(a0 * inv) | ((unsigned)f2bf(a1 * inv) << 16);
    o.y = (unsigned)f2bf(a2 * inv) | ((unsigned)f2bf(a3 * inv) << 16);
    o.z = (unsigned)f2bf(a4 * inv) | ((unsigned)f2bf(a5 * inv) << 16);
    o.w = (unsigned)f2bf(a6 * inv) | ((unsigned)f2bf(a7 * inv) << 16);
    *(uint4*)((char*)AGG + (size_t)n * 256 + f * 16) = o;
}

// ---------------- fused SAGE linear via MFMA (layer 1: writes Y) ----------------
__global__ __launch_bounds__(256) void gemm_kernel(const unsigned short* __restrict__ A0,
                                                   const unsigned short* __restrict__ A1,
                                                   const unsigned short* __restrict__ wblob,
                                                   const float* __restrict__ bias,
                                                   unsigned short* __restrict__ Y) {
    __shared__ char lds[65536];
    const int t = threadIdx.x, lane = t & 63, w = t >> 6;
    const int row0 = blockIdx.x * 128 + w * 32;

    {
        const char* src = (const char*)wblob + w * 16384 + lane * 16;
        char* dst = lds + w * 16384;
#pragma unroll
        for (int i = 0; i < 16; ++i) {
            __builtin_amdgcn_global_load_lds(
                (const __attribute__((address_space(1))) unsigned*)(src + i * 1024),
                (__attribute__((address_space(3))) unsigned*)(dst + i * 1024), 16, 0, 0);
        }
    }
    __syncthreads();

    f32x4 acc[2][8];
#pragma unroll
    for (int rt = 0; rt < 2; ++rt)
#pragma unroll
        for (int tl = 0; tl < 8; ++tl) acc[rt][tl] = (f32x4){0.f, 0.f, 0.f, 0.f};

    int rA = min(row0 + (lane & 15),      N_NODES - 1);
    int rB = min(row0 + 16 + (lane & 15), N_NODES - 1);
    const int kl = (lane >> 4) * 8;

#pragma unroll
    for (int km = 0; km < 8; ++km) {
        const unsigned short* A = (km < 4) ? A0 : A1;
        int k0 = (km & 3) * 32 + kl;
        bf16x8 a0 = *(const bf16x8*)(A + (size_t)rA * 128 + k0);
        bf16x8 a1 = *(const bf16x8*)(A + (size_t)rB * 128 + k0);
        const char* bbase = lds + km * 8192 + lane * 16;
#pragma unroll
        for (int tile = 0; tile < 8; ++tile) {
            bf16x8 b = *(const bf16x8*)(bbase + tile * 1024);
            acc[0][tile] = __builtin_amdgcn_mfma_f32_16x16x32_bf16(a0, b, acc[0][tile], 0, 0, 0);
            acc[1][tile] = __builtin_amdgcn_mfma_f32_16x16x32_bf16(a1, b, acc[1][tile], 0, 0, 0);
        }
    }

    const int c     = lane & 15;
    const int rbase = (lane >> 4) * 4;
#pragma unroll
    for (int rt = 0; rt < 2; ++rt) {
#pragma unroll
        for (int tile = 0; tile < 8; ++tile) {
            int col = tile * 16 + c;
            float bv = bias[col];
#pragma unroll
            for (int j = 0; j < 4; ++j) {
                int r = row0 + rt * 16 + rbase + j;
                if (r < N_NODES)
                    Y[(size_t)r * 128 + col] = f2bf(fmaxf(acc[rt][tile][j] + bv, 0.f));
            }
        }
    }
}

// ---------------- layer-2 GEMM with fused mean-pool (no y2 write) ----------------
__global__ __launch_bounds__(256) void gemm_pool_kernel(const unsigned short* __restrict__ A0,
                                                        const unsigned short* __restrict__ A1,
                                                        const unsigned short* __restrict__ wblob,
                                                        const float* __restrict__ bias,
                                                        const int* __restrict__ batch,
                                                        float* __restrict__ gsum) {
    __shared__ char lds[65536];
    const int t = threadIdx.x, lane = t & 63, w = t >> 6;
    const int brow0 = blockIdx.x * 128;
    const int row0  = brow0 + w * 32;

    {
        const char* src = (const char*)wblob + w * 16384 + lane * 16;
        char* dst = lds + w * 16384;
#pragma unroll
        for (int i = 0; i < 16; ++i) {
            __builtin_amdgcn_global_load_lds(
                (const __attribute__((address_space(1))) unsigned*)(src + i * 1024),
                (__attribute__((address_space(3))) unsigned*)(dst + i * 1024), 16, 0, 0);
        }
    }
    __syncthreads();

    f32x4 acc[2][8];
#pragma unroll
    for (int rt = 0; rt < 2; ++rt)
#pragma unroll
        for (int tl = 0; tl < 8; ++tl) acc[rt][tl] = (f32x4){0.f, 0.f, 0.f, 0.f};

    int rA = min(row0 + (lane & 15),      N_NODES - 1);
    int rB = min(row0 + 16 + (lane & 15), N_NODES - 1);
    const int kl = (lane >> 4) * 8;

#pragma unroll
    for (int km = 0; km < 8; ++km) {
        const unsigned short* A = (km < 4) ? A0 : A1;
        int k0 = (km & 3) * 32 + kl;
        bf16x8 a0 = *(const bf16x8*)(A + (size_t)rA * 128 + k0);
        bf16x8 a1 = *(const bf16x8*)(A + (size_t)rB * 128 + k0);
        const char* bbase = lds + km * 8192 + lane * 16;
#pragma unroll
        for (int tile = 0; tile < 8; ++tile) {
            bf16x8 b = *(const bf16x8*)(bbase + tile * 1024);
            acc[0][tile] = __builtin_amdgcn_mfma_f32_16x16x32_bf16(a0, b, acc[0][tile], 0, 0, 0);
            acc[1][tile] = __builtin_amdgcn_mfma_f32_16x16x32_bf16(a1, b, acc[1][tile], 0, 0, 0);
        }
    }

    // epilogue: relu(acc+bias) -> reuse weight LDS as 128x128 f32 tile
    __syncthreads();                       // all waves done reading weights
    float* ftile = (float*)lds;
    const int c     = lane & 15;
    const int rbase = (lane >> 4) * 4;
#pragma unroll
    for (int rt = 0; rt < 2; ++rt) {
#pragma unroll
        for (int tile = 0; tile < 8; ++tile) {
            int col = tile * 16 + c;
            float bv = bias[col];
#pragma unroll
            for (int j = 0; j < 4; ++j) {
                int lr = w * 32 + rt * 16 + rbase + j;
                ftile[lr * 128 + col] = fmaxf(acc[rt][tile][j] + bv, 0.f);
            }
        }
    }
    __syncthreads();

    // per-graph column partial sums (batch sorted): thread = (col, row-half)
    const int col  = t & 127;
    const int half = t >> 7;
    float s = 0.f;
    int curg = -1;
    for (int rr = 0; rr < 64; ++rr) {
        int r = brow0 + half * 64 + rr;
        if (r >= N_NODES) break;
        int g = batch[r];
        if (g != curg) {
            if (curg >= 0) atomicAdd(&gsum[curg * 128 + col], s);
            curg = g; s = 0.f;
        }
        s += ftile[(half * 64 + rr) * 128 + col];
    }
    if (curg >= 0) atomicAdd(&gsum[curg * 128 + col], s);
}

// ---------------- classifier ----------------
__global__ void final_kernel(const float* __restrict__ gsum, const int* __restrict__ batch,
                             const float* __restrict__ linW, const float* __restrict__ linb,
                             float* __restrict__ out) {
    int t = blockIdx.x * 256 + threadIdx.x;
    if (t >= N_GRAPHS * 10) return;
    int g = t / 10, j = t % 10;
    int bnd[2];
    for (int c = 0; c < 2; ++c) {
        int target = g + c;
        int lo = 0, hi = N_NODES;
        while (lo < hi) { int mid = (lo + hi) >> 1; if (batch[mid] < target) lo = mid + 1; else hi = mid; }
        bnd[c] = lo;
    }
    float invc = 1.f / (float)max(bnd[1] - bnd[0], 1);
    float s = 0.f;
    for (int k = 0; k < 128; ++k) s += gsum[g * 128 + k] * linW[j * 128 + k];
    out[t] = linb[j] + s * invc;
}

extern "C" void kernel_launch(void* const* d_in, const int* in_sizes, int n_in,
                              void* d_out, int out_size, void* d_ws, size_t ws_size,
                              hipStream_t stream) {
    const int*   x_idx = (const int*)d_in[0];
    const int*   eidx  = (const int*)d_in[1];   // [2][N_EDGES]
    const int*   batch = (const int*)d_in[2];
    const float* table = (const float*)d_in[3];
    const float* Wl1   = (const float*)d_in[4];
    const float* bl1   = (const float*)d_in[5];
    const float* Wr1   = (const float*)d_in[6];
    const float* Wl2   = (const float*)d_in[7];
    const float* bl2   = (const float*)d_in[8];
    const float* Wr2   = (const float*)d_in[9];
    const float* linW  = (const float*)d_in[10];
    const float* linb  = (const float*)d_in[11];
    float*       out   = (float*)d_out;

    const int* src = eidx;
    const int* dst = eidx + N_EDGES;

    // workspace layout (~55 MB); feature buffers row-major [N][128] bf16
    unsigned short* X    = (unsigned short*)d_ws;                 // x0
    unsigned short* AGG  = X   + (size_t)N_NODES * 128;           // agg
    unsigned short* Y1   = AGG + (size_t)N_NODES * 128;           // y1
    unsigned short* blob = Y1  + (size_t)N_NODES * 128;           // 2 x 64KB frag-ordered
    float* gsum = (float*)(blob + 65536);
    int* cnt    = (int*)(gsum + N_GRAPHS * 128);
    int* rowptr = cnt + N_NODES;                                  // N_NODES+1
    int* csr    = rowptr + (N_NODES + 1);                         // N_EDGES
    int* bsum   = csr + N_EDGES;                                  // SCAN_BLOCKS
    int* part   = bsum + SCAN_BLOCKS;                             // NCHUNK x N_NODES
    int* off    = part + (size_t)NCHUNK * N_NODES;                // NCHUNK x N_NODES

    // k1: histogram | embed | weight prep + gsum zero (one launch)
    k1_kernel<<<K1_HIST + K1_EMBED + K1_PREP, 256, 0, stream>>>(
        dst, part, x_idx, table, X, Wl1, Wr1, Wl2, Wr2, blob, gsum);
    cntsum_kernel   <<<SCAN_BLOCKS, 256, 0, stream>>>(part, cnt, bsum);
    rowptroff_kernel<<<SCAN_BLOCKS, 256, 0, stream>>>(cnt, bsum, part, rowptr, off);
    scatter_kernel  <<<NCHUNK * NRANGE, 256, 0, stream>>>(src, dst, off, csr);

    // layer 1
    agg_kernel <<<dim3(N_NODES / 16), 256, 0, stream>>>(X, rowptr, csr, AGG);
    gemm_kernel<<<dim3((N_NODES + 127) / 128), 256, 0, stream>>>(AGG, X, blob, bl1, Y1);
    // layer 2 (+ fused mean pool)
    agg_kernel      <<<dim3(N_NODES / 16), 256, 0, stream>>>(Y1, rowptr, csr, AGG);
    gemm_pool_kernel<<<dim3((N_NODES + 127) / 128), 256, 0, stream>>>(AGG, Y1, blob + 32768, bl2, batch, gsum);

    final_kernel<<<3, 256, 0, stream>>>(gsum, batch, linW, linb, out);
}

// Round 8
// 152.518 us; speedup vs baseline: 1.1782x; 1.0064x over previous
//
#include <hip/hip_runtime.h>

#define N_NODES 50000
#define N_EDGES 800000
#define N_GRAPHS 64
#define SCAN_BLOCKS 196              // 196*256 = 50176 >= N_NODES

// CSR build partitioning: zero device atomics
#define NCHUNK 32
#define CHUNK_E (N_EDGES / NCHUNK)   // 25000
#define NRANGE 4
#define RSZ (N_NODES / NRANGE)       // 12500 counters = 50KB LDS

// fat k1 partition
#define K1_HIST (NCHUNK * NRANGE)    // 128 blocks
#define K1_EMBED (N_NODES * 16 / 256) // 3125 blocks
#define K1_PREP 32                   // 8192 threads: weight prep + gsum zero

// quarter-major feature layout: [4][N_NODES][32 feats] bf16 (64B rows)
#define QUS (N_NODES * 32)           // ushorts per quarter

// agg grid: quarter = blockIdx & 3 (fastest-varying -> XCD-pinned), 64 nodes/block
#define AGG_NB ((N_NODES + 63) / 64) // 782

typedef __bf16 bf16x8 __attribute__((ext_vector_type(8)));
typedef float f32x4 __attribute__((ext_vector_type(4)));

// ---- bf16 helpers (RN-even pack, exact unpack) ----
static __device__ __forceinline__ unsigned short f2bf(float f) {
    union { float f; unsigned u; } v; v.f = f;
    unsigned u = v.u;
    u += 0x7fffu + ((u >> 16) & 1u);          // round-to-nearest-even
    return (unsigned short)(u >> 16);
}
static __device__ __forceinline__ float bflo(unsigned w) {
    union { unsigned u; float f; } v; v.u = w << 16; return v.f;
}
static __device__ __forceinline__ float bfhi(unsigned w) {
    union { unsigned u; float f; } v; v.u = w & 0xffff0000u; return v.f;
}

// ---------------- k1: histpart | embed | weight-prep + gsum zero ----------------
__global__ __launch_bounds__(256) void k1_kernel(const int* __restrict__ dst,
                                                 int* __restrict__ part,
                                                 const int* __restrict__ x_idx,
                                                 const float* __restrict__ table,
                                                 unsigned short* __restrict__ X,
                                                 const float* __restrict__ Wl1,
                                                 const float* __restrict__ Wr1,
                                                 const float* __restrict__ Wl2,
                                                 const float* __restrict__ Wr2,
                                                 unsigned short* __restrict__ blob,
                                                 float* __restrict__ gsum) {
    const int b = blockIdx.x;
    if (b < K1_HIST) {
        // ---- per-(chunk,range) LDS histogram of dst ----
        __shared__ int h[RSZ];
        const int c = b >> 2;            // chunk
        const int r = b & 3;             // node range
        const int rbase = r * RSZ;
        for (int i = threadIdx.x; i < RSZ; i += 256) h[i] = 0;
        __syncthreads();
        const int4* d4 = (const int4*)(dst + c * CHUNK_E);
        for (int i = threadIdx.x; i < CHUNK_E / 4; i += 256) {
            int4 d = d4[i];
            unsigned a;
            a = (unsigned)(d.x - rbase); if (a < RSZ) atomicAdd(&h[a], 1);
            a = (unsigned)(d.y - rbase); if (a < RSZ) atomicAdd(&h[a], 1);
            a = (unsigned)(d.z - rbase); if (a < RSZ) atomicAdd(&h[a], 1);
            a = (unsigned)(d.w - rbase); if (a < RSZ) atomicAdd(&h[a], 1);
        }
        __syncthreads();
        int* p = part + (size_t)c * N_NODES + rbase;
        for (int i = threadIdx.x; i < RSZ; i += 256) p[i] = h[i];
    } else if (b < K1_HIST + K1_EMBED) {
        // ---- embedding gather -> bf16, quarter-major store ----
        int i = (b - K1_HIST) * 256 + threadIdx.x;   // node*16 + 8-feat chunk
        int n = i >> 4, cq = i & 15;
        const float4* src = (const float4*)(table + (size_t)x_idx[n] * 128 + cq * 8);
        float4 a = src[0], bb = src[1];
        uint4 o;
        o.x = (unsigned)f2bf(a.x)  | ((unsigned)f2bf(a.y)  << 16);
        o.y = (unsigned)f2bf(a.z)  | ((unsigned)f2bf(a.w)  << 16);
        o.z = (unsigned)f2bf(bb.x) | ((unsigned)f2bf(bb.y) << 16);
        o.w = (unsigned)f2bf(bb.z) | ((unsigned)f2bf(bb.w) << 16);
        int qq = cq >> 2;                            // quarter
        ((uint4*)X)[(size_t)qq * (N_NODES * 4) + n * 4 + (cq & 3)] = o;
    } else {
        // ---- weight prep (frag-ordered bf16 blob) + gsum zero ----
        int s = (b - K1_HIST - K1_EMBED) * 256 + threadIdx.x;   // [0, 8192)
        gsum[s] = 0.f;
        int g = s >> 12;
        int sl = s & 4095;
        int fidx = sl >> 6, lane = sl & 63;
        int m = fidx >> 5, kk = (fidx >> 3) & 3, tile = fidx & 7;
        const float* W = g ? (m ? Wr2 : Wl2) : (m ? Wr1 : Wl1);
        int n  = tile * 16 + (lane & 15);
        int k0 = kk * 32 + (lane >> 4) * 8;
        const float4* src = (const float4*)(W + n * 128 + k0);
        float4 a = src[0], bb = src[1];
        uint4 o;
        o.x = (unsigned)f2bf(a.x)  | ((unsigned)f2bf(a.y)  << 16);
        o.y = (unsigned)f2bf(a.z)  | ((unsigned)f2bf(a.w)  << 16);
        o.z = (unsigned)f2bf(bb.x) | ((unsigned)f2bf(bb.y) << 16);
        o.w = (unsigned)f2bf(bb.z) | ((unsigned)f2bf(bb.w) << 16);
        ((uint4*)blob)[s] = o;
    }
}

// ---------------- cnt + per-block sum (fused) ----------------
__global__ __launch_bounds__(256) void cntsum_kernel(const int* __restrict__ part,
                                                     int* __restrict__ cnt,
                                                     int* __restrict__ bsum) {
    int t = threadIdx.x;
    int n = blockIdx.x * 256 + t;
    int s = 0;
    if (n < N_NODES) {
#pragma unroll
        for (int c = 0; c < NCHUNK; ++c) s += part[(size_t)c * N_NODES + n];
        cnt[n] = s;
    }
#pragma unroll
    for (int off = 32; off > 0; off >>= 1) s += __shfl_down(s, off, 64);
    __shared__ int ws[4];
    if ((t & 63) == 0) ws[t >> 6] = s;
    __syncthreads();
    if (t == 0) bsum[blockIdx.x] = ws[0] + ws[1] + ws[2] + ws[3];
}

// ---------------- rowptr + per-chunk offsets (with inline block-offset scan) ----------------
__global__ __launch_bounds__(256) void rowptroff_kernel(const int* __restrict__ cnt,
                                                        const int* __restrict__ bsum,
                                                        const int* __restrict__ part,
                                                        int* __restrict__ rowptr,
                                                        int* __restrict__ off) {
    __shared__ int sb[256];
    __shared__ int sd[256];
    int t = threadIdx.x;
    sb[t] = (t < SCAN_BLOCKS) ? bsum[t] : 0;
    __syncthreads();
    for (int o = 1; o < 256; o <<= 1) {
        int add = (t >= o) ? sb[t - o] : 0;
        __syncthreads();
        sb[t] += add;
        __syncthreads();
    }
    int boff = (blockIdx.x > 0) ? sb[blockIdx.x - 1] : 0;

    int i = blockIdx.x * 256 + t;
    int v = (i < N_NODES) ? cnt[i] : 0;
    sd[t] = v;
    __syncthreads();
    for (int o = 1; o < 256; o <<= 1) {
        int add = (t >= o) ? sd[t - o] : 0;
        __syncthreads();
        sd[t] += add;
        __syncthreads();
    }
    int excl = sd[t] - v + boff;
    if (i < N_NODES) {
        rowptr[i] = excl;
        if (i == N_NODES - 1) rowptr[N_NODES] = excl + v;
        int run = excl;
#pragma unroll
        for (int c = 0; c < NCHUNK; ++c) {
            off[(size_t)c * N_NODES + i] = run;
            run += part[(size_t)c * N_NODES + i];
        }
    }
}

// ---------------- scatter, LDS position counters, no device atomics ----------------
__global__ __launch_bounds__(256) void scatter_kernel(const int* __restrict__ src,
                                                      const int* __restrict__ dst,
                                                      const int* __restrict__ off,
                                                      int* __restrict__ csr) {
    __shared__ int h[RSZ];
    const int c = blockIdx.x >> 2;
    const int r = blockIdx.x & 3;
    const int rbase = r * RSZ;
    const int* o = off + (size_t)c * N_NODES + rbase;
    for (int i = threadIdx.x; i < RSZ; i += 256) h[i] = o[i];
    __syncthreads();
    const int4* d4 = (const int4*)(dst + c * CHUNK_E);
    const int4* s4 = (const int4*)(src + c * CHUNK_E);
    for (int i = threadIdx.x; i < CHUNK_E / 4; i += 256) {
        int4 d = d4[i];
        int4 s = s4[i];
        unsigned a;
        a = (unsigned)(d.x - rbase); if (a < RSZ) csr[atomicAdd(&h[a], 1)] = s.x;
        a = (unsigned)(d.y - rbase); if (a < RSZ) csr[atomicAdd(&h[a], 1)] = s.y;
        a = (unsigned)(d.z - rbase); if (a < RSZ) csr[atomicAdd(&h[a], 1)] = s.z;
        a = (unsigned)(d.w - rbase); if (a < RSZ) csr[atomicAdd(&h[a], 1)] = s.w;
    }
}

// ---------------- mean aggregation, XCD-pinned quarter slices ----------------
// quarter = blockIdx & 3 (FASTEST-varying): round-robin block->XCD dispatch means
// XCD k only ever processes quarter k&3 -> 3.2MB working set, L2-resident.
// wave = 16 nodes x 4 lanes; lane f = 16B of the 64B quarter-row.
__global__ __launch_bounds__(256) void agg_kernel(const unsigned short* __restrict__ Xq,
                                                  const int* __restrict__ rowptr,
                                                  const int* __restrict__ csr,
                                                  unsigned short* __restrict__ AGGq) {
    const int t = threadIdx.x;
    const int lane = t & 63;
    const int q = blockIdx.x & 3;
    const int n = (blockIdx.x >> 2) * 64 + (t >> 6) * 16 + (lane >> 2);
    const int f = lane & 3;
    if (n >= N_NODES) return;
    int beg = rowptr[n], end = rowptr[n + 1];
    const char* Xb = (const char*)(Xq + (size_t)q * QUS) + f * 16;
    float a0 = 0.f, a1 = 0.f, a2 = 0.f, a3 = 0.f,
          a4 = 0.f, a5 = 0.f, a6 = 0.f, a7 = 0.f;
    int i = beg;
    for (; i + 4 <= end; i += 4) {
        int s0 = csr[i], s1 = csr[i + 1], s2 = csr[i + 2], s3 = csr[i + 3];
        uint4 v0 = *(const uint4*)(Xb + (size_t)s0 * 64);
        uint4 v1 = *(const uint4*)(Xb + (size_t)s1 * 64);
        uint4 v2 = *(const uint4*)(Xb + (size_t)s2 * 64);
        uint4 v3 = *(const uint4*)(Xb + (size_t)s3 * 64);
        a0 += (bflo(v0.x) + bflo(v1.x)) + (bflo(v2.x) + bflo(v3.x));
        a1 += (bfhi(v0.x) + bfhi(v1.x)) + (bfhi(v2.x) + bfhi(v3.x));
        a2 += (bflo(v0.y) + bflo(v1.y)) + (bflo(v2.y) + bflo(v3.y));
        a3 += (bfhi(v0.y) + bfhi(v1.y)) + (bfhi(v2.y) + bfhi(v3.y));
        a4 += (bflo(v0.z) + bflo(v1.z)) + (bflo(v2.z) + bflo(v3.z));
        a5 += (bfhi(v0.z) + bfhi(v1.z)) + (bfhi(v2.z) + bfhi(v3.z));
        a6 += (bflo(v0.w) + bflo(v1.w)) + (bflo(v2.w) + bflo(v3.w));
        a7 += (bfhi(v0.w) + bfhi(v1.w)) + (bfhi(v2.w) + bfhi(v3.w));
    }
    for (; i < end; ++i) {
        uint4 v0 = *(const uint4*)(Xb + (size_t)csr[i] * 64);
        a0 += bflo(v0.x); a1 += bfhi(v0.x);
        a2 += bflo(v0.y); a3 += bfhi(v0.y);
        a4 += bflo(v0.z); a5 += bfhi(v0.z);
        a6 += bflo(v0.w); a7 += bfhi(v0.w);
    }
    float inv = 1.f / (float)max(end - beg, 1);
    uint4 o;
    o.x = (unsigned)f2bf(a0 * inv) | ((unsigned)f2bf(a1 * inv) << 16);
    o.y = (unsigned)f2bf(a2 * inv) | ((unsigned)f2bf(a3 * inv) << 16);
    o.z = (unsigned)f2bf(a4 * inv) | ((unsigned)f2bf(a5 * inv) << 16);
    o.w = (unsigned)f2bf(a6 * inv) | ((unsigned)f2bf(a7 * inv) << 16);
    *(uint4*)((char*)(AGGq + (size_t)q * QUS) + (size_t)n * 64 + f * 16) = o;
}

// ---------------- fused SAGE linear via MFMA (layer 1: writes quartered Y) ----------------
// A0/A1/Y quarter-major [4][N][32]. k-fragment quarter = km&3 (aligned by design).
__global__ __launch_bounds__(256) void gemm_kernel(const unsigned short* __restrict__ A0,
                                                   const unsigned short* __restrict__ A1,
                                                   const unsigned short* __restrict__ wblob,
                                                   const float* __restrict__ bias,
                                                   unsigned short* __restrict__ Y) {
    __shared__ char lds[65536];
    const int t = threadIdx.x, lane = t & 63, w = t >> 6;
    const int row0 = blockIdx.x * 128 + w * 32;

    {
        const char* src = (const char*)wblob + w * 16384 + lane * 16;
        char* dst = lds + w * 16384;
#pragma unroll
        for (int i = 0; i < 16; ++i) {
            __builtin_amdgcn_global_load_lds(
                (const __attribute__((address_space(1))) unsigned*)(src + i * 1024),
                (__attribute__((address_space(3))) unsigned*)(dst + i * 1024), 16, 0, 0);
        }
    }
    __syncthreads();

    f32x4 acc[2][8];
#pragma unroll
    for (int rt = 0; rt < 2; ++rt)
#pragma unroll
        for (int tl = 0; tl < 8; ++tl) acc[rt][tl] = (f32x4){0.f, 0.f, 0.f, 0.f};

    int rA = min(row0 + (lane & 15),      N_NODES - 1);
    int rB = min(row0 + 16 + (lane & 15), N_NODES - 1);
    const int kl = (lane >> 4) * 8;          // ushort offset within quarter row

#pragma unroll
    for (int km = 0; km < 8; ++km) {
        const unsigned short* Aq = ((km < 4) ? A0 : A1) + (size_t)(km & 3) * QUS;
        bf16x8 a0 = *(const bf16x8*)(Aq + (size_t)rA * 32 + kl);
        bf16x8 a1 = *(const bf16x8*)(Aq + (size_t)rB * 32 + kl);
        const char* bbase = lds + km * 8192 + lane * 16;
#pragma unroll
        for (int tile = 0; tile < 8; ++tile) {
            bf16x8 b = *(const bf16x8*)(bbase + tile * 1024);
            acc[0][tile] = __builtin_amdgcn_mfma_f32_16x16x32_bf16(a0, b, acc[0][tile], 0, 0, 0);
            acc[1][tile] = __builtin_amdgcn_mfma_f32_16x16x32_bf16(a1, b, acc[1][tile], 0, 0, 0);
        }
    }

    const int c     = lane & 15;
    const int rbase = (lane >> 4) * 4;
#pragma unroll
    for (int rt = 0; rt < 2; ++rt) {
#pragma unroll
        for (int tile = 0; tile < 8; ++tile) {
            int col = tile * 16 + c;
            float bv = bias[col];
            int q = col >> 5, wc = col & 31;
#pragma unroll
            for (int j = 0; j < 4; ++j) {
                int r = row0 + rt * 16 + rbase + j;
                if (r < N_NODES)
                    Y[(size_t)q * QUS + (size_t)r * 32 + wc] =
                        f2bf(fmaxf(acc[rt][tile][j] + bv, 0.f));
            }
        }
    }
}

// ---------------- layer-2 GEMM with fused mean-pool (no y2 write) ----------------
__global__ __launch_bounds__(256) void gemm_pool_kernel(const unsigned short* __restrict__ A0,
                                                        const unsigned short* __restrict__ A1,
                                                        const unsigned short* __restrict__ wblob,
                                                        const float* __restrict__ bias,
                                                        const int* __restrict__ batch,
                                                        float* __restrict__ gsum) {
    __shared__ char lds[65536];
    const int t = threadIdx.x, lane = t & 63, w = t >> 6;
    const int brow0 = blockIdx.x * 128;
    const int row0  = brow0 + w * 32;

    {
        const char* src = (const char*)wblob + w * 16384 + lane * 16;
        char* dst = lds + w * 16384;
#pragma unroll
        for (int i = 0; i < 16; ++i) {
            __builtin_amdgcn_global_load_lds(
                (const __attribute__((address_space(1))) unsigned*)(src + i * 1024),
                (__attribute__((address_space(3))) unsigned*)(dst + i * 1024), 16, 0, 0);
        }
    }
    __syncthreads();

    f32x4 acc[2][8];
#pragma unroll
    for (int rt = 0; rt < 2; ++rt)
#pragma unroll
        for (int tl = 0; tl < 8; ++tl) acc[rt][tl] = (f32x4){0.f, 0.f, 0.f, 0.f};

    int rA = min(row0 + (lane & 15),      N_NODES - 1);
    int rB = min(row0 + 16 + (lane & 15), N_NODES - 1);
    const int kl = (lane >> 4) * 8;

#pragma unroll
    for (int km = 0; km < 8; ++km) {
        const unsigned short* Aq = ((km < 4) ? A0 : A1) + (size_t)(km & 3) * QUS;
        bf16x8 a0 = *(const bf16x8*)(Aq + (size_t)rA * 32 + kl);
        bf16x8 a1 = *(const bf16x8*)(Aq + (size_t)rB * 32 + kl);
        const char* bbase = lds + km * 8192 + lane * 16;
#pragma unroll
        for (int tile = 0; tile < 8; ++tile) {
            bf16x8 b = *(const bf16x8*)(bbase + tile * 1024);
            acc[0][tile] = __builtin_amdgcn_mfma_f32_16x16x32_bf16(a0, b, acc[0][tile], 0, 0, 0);
            acc[1][tile] = __builtin_amdgcn_mfma_f32_16x16x32_bf16(a1, b, acc[1][tile], 0, 0, 0);
        }
    }

    // epilogue: relu(acc+bias) -> reuse weight LDS as 128x128 f32 tile
    __syncthreads();                       // all waves done reading weights
    float* ftile = (float*)lds;
    const int c     = lane & 15;
    const int rbase = (lane >> 4) * 4;
#pragma unroll
    for (int rt = 0; rt < 2; ++rt) {
#pragma unroll
        for (int tile = 0; tile < 8; ++tile) {
            int col = tile * 16 + c;
            float bv = bias[col];
#pragma unroll
            for (int j = 0; j < 4; ++j) {
                int lr = w * 32 + rt * 16 + rbase + j;
                ftile[lr * 128 + col] = fmaxf(acc[rt][tile][j] + bv, 0.f);
            }
        }
    }
    __syncthreads();

    // per-graph column partial sums (batch sorted): thread = (col, row-half)
    const int col  = t & 127;
    const int half = t >> 7;
    float s = 0.f;
    int curg = -1;
    for (int rr = 0; rr < 64; ++rr) {
        int r = brow0 + half * 64 + rr;
        if (r >= N_NODES) break;
        int g = batch[r];
        if (g != curg) {
            if (curg >= 0) atomicAdd(&gsum[curg * 128 + col], s);
            curg = g; s = 0.f;
        }
        s += ftile[(half * 64 + rr) * 128 + col];
    }
    if (curg >= 0) atomicAdd(&gsum[curg * 128 + col], s);
}

// ---------------- classifier ----------------
__global__ void final_kernel(const float* __restrict__ gsum, const int* __restrict__ batch,
                             const float* __restrict__ linW, const float* __restrict__ linb,
                             float* __restrict__ out) {
    int t = blockIdx.x * 256 + threadIdx.x;
    if (t >= N_GRAPHS * 10) return;
    int g = t / 10, j = t % 10;
    int bnd[2];
    for (int c = 0; c < 2; ++c) {
        int target = g + c;
        int lo = 0, hi = N_NODES;
        while (lo < hi) { int mid = (lo + hi) >> 1; if (batch[mid] < target) lo = mid + 1; else hi = mid; }
        bnd[c] = lo;
    }
    float invc = 1.f / (float)max(bnd[1] - bnd[0], 1);
    float s = 0.f;
    for (int k = 0; k < 128; ++k) s += gsum[g * 128 + k] * linW[j * 128 + k];
    out[t] = linb[j] + s * invc;
}

extern "C" void kernel_launch(void* const* d_in, const int* in_sizes, int n_in,
                              void* d_out, int out_size, void* d_ws, size_t ws_size,
                              hipStream_t stream) {
    const int*   x_idx = (const int*)d_in[0];
    const int*   eidx  = (const int*)d_in[1];   // [2][N_EDGES]
    const int*   batch = (const int*)d_in[2];
    const float* table = (const float*)d_in[3];
    const float* Wl1   = (const float*)d_in[4];
    const float* bl1   = (const float*)d_in[5];
    const float* Wr1   = (const float*)d_in[6];
    const float* Wl2   = (const float*)d_in[7];
    const float* bl2   = (const float*)d_in[8];
    const float* Wr2   = (const float*)d_in[9];
    const float* linW  = (const float*)d_in[10];
    const float* linb  = (const float*)d_in[11];
    float*       out   = (float*)d_out;

    const int* src = eidx;
    const int* dst = eidx + N_EDGES;

    // workspace layout (~55 MB); feature buffers quarter-major [4][N][32]
    unsigned short* X    = (unsigned short*)d_ws;                 // x0
    unsigned short* AGG  = X   + (size_t)N_NODES * 128;           // agg
    unsigned short* Y1   = AGG + (size_t)N_NODES * 128;           // y1
    unsigned short* blob = Y1  + (size_t)N_NODES * 128;           // 2 x 64KB frag-ordered
    float* gsum = (float*)(blob + 65536);
    int* cnt    = (int*)(gsum + N_GRAPHS * 128);
    int* rowptr = cnt + N_NODES;                                  // N_NODES+1
    int* csr    = rowptr + (N_NODES + 1);                         // N_EDGES
    int* bsum   = csr + N_EDGES;                                  // SCAN_BLOCKS
    int* part   = bsum + SCAN_BLOCKS;                             // NCHUNK x N_NODES
    int* off    = part + (size_t)NCHUNK * N_NODES;                // NCHUNK x N_NODES

    // k1: histogram | embed | weight prep + gsum zero (one launch)
    k1_kernel<<<K1_HIST + K1_EMBED + K1_PREP, 256, 0, stream>>>(
        dst, part, x_idx, table, X, Wl1, Wr1, Wl2, Wr2, blob, gsum);
    cntsum_kernel   <<<SCAN_BLOCKS, 256, 0, stream>>>(part, cnt, bsum);
    rowptroff_kernel<<<SCAN_BLOCKS, 256, 0, stream>>>(cnt, bsum, part, rowptr, off);
    scatter_kernel  <<<NCHUNK * NRANGE, 256, 0, stream>>>(src, dst, off, csr);

    // layer 1
    agg_kernel <<<dim3(AGG_NB * 4), 256, 0, stream>>>(X, rowptr, csr, AGG);
    gemm_kernel<<<dim3((N_NODES + 127) / 128), 256, 0, stream>>>(AGG, X, blob, bl1, Y1);
    // layer 2 (+ fused mean pool)
    agg_kernel      <<<dim3(AGG_NB * 4), 256, 0, stream>>>(Y1, rowptr, csr, AGG);
    gemm_pool_kernel<<<dim3((N_NODES + 127) / 128), 256, 0, stream>>>(AGG, Y1, blob + 32768, bl2, batch, gsum);

    final_kernel<<<3, 256, 0, stream>>>(gsum, batch, linW, linb, out);
}